// Round 1
// baseline (2515.631 us; speedup 1.0000x reference)
//
#include <hip/hip_runtime.h>

#define BATCH 16
#define TFRAMES 2000
#define BINS 513
#define NFFT 1024
#define STEP 256
#define OUT_LEN 512768          // (TFRAMES-1)*STEP + NFFT
#define M_TOTAL (BATCH*TFRAMES) // 32000

#define MT 64
#define NT 64
#define KT 16
#define PAD 4                   // MT+PAD = 68 floats/row: 16B-aligned rows, 2-way-max bank aliasing

__global__ __launch_bounds__(256) void istft_gemm_ola(
    const float* __restrict__ sre, const float* __restrict__ sim,
    const float* __restrict__ dcos, const float* __restrict__ dsin,
    const float* __restrict__ window, float* __restrict__ out)
{
    __shared__ float As_re[KT][MT + PAD];
    __shared__ float As_im[KT][MT + PAD];
    __shared__ float Bs_c[KT][NT + PAD];
    __shared__ float Bs_s[KT][NT + PAD];

    const int ntile = blockIdx.x & 15;   // 16 n-tiles fastest -> A-tile L2 reuse
    const int mtile = blockIdx.x >> 4;   // 500 m-tiles
    const int m0 = mtile * MT;
    const int n0 = ntile * NT;

    const int tid = threadIdx.x;
    const int tx = tid & 15;             // n direction (4 cols each)
    const int ty = tid >> 4;             // m direction (4 rows each)

    const int lcol = tid & 15;           // k within chunk
    const int lrow = tid >> 4;           // row group

    float acc[4][4] = {};

    for (int k0 = 0; k0 < BINS; k0 += KT) {
        const int k = k0 + lcol;
        const bool kvalid = (k < BINS);
        // Hermitian fold weight: bins 1..511 appear twice in the full spectrum
        const float w = kvalid ? ((k == 0 || k == 512) ? (1.0f/1024.0f) : (2.0f/1024.0f))
                               : 0.0f;
        #pragma unroll
        for (int i = 0; i < 4; i++) {
            const int m = m0 + lrow + i*16;          // M_TOTAL % MT == 0, always valid
            const size_t base = (size_t)m * BINS + k;
            const float re = kvalid ? sre[base] : 0.0f;
            const float im = kvalid ? sim[base] : 0.0f;
            As_re[lcol][lrow + i*16] =  w * re;
            As_im[lcol][lrow + i*16] = -w * im;      // minus sign from (cos - i sin) einsum
        }
        #pragma unroll
        for (int i = 0; i < 4; i++) {
            const int n = n0 + lrow + i*16;
            const size_t base = (size_t)n * NFFT + k;
            Bs_c[lcol][lrow + i*16] = kvalid ? dcos[base] : 0.0f;
            Bs_s[lcol][lrow + i*16] = kvalid ? dsin[base] : 0.0f;
        }
        __syncthreads();

        #pragma unroll
        for (int kk = 0; kk < KT; kk++) {
            const float4 ar = *(const float4*)&As_re[kk][ty*4];
            const float4 ai = *(const float4*)&As_im[kk][ty*4];
            const float4 bc = *(const float4*)&Bs_c[kk][tx*4];
            const float4 bs = *(const float4*)&Bs_s[kk][tx*4];
            const float a_r[4] = {ar.x, ar.y, ar.z, ar.w};
            const float a_i[4] = {ai.x, ai.y, ai.z, ai.w};
            const float b_c[4] = {bc.x, bc.y, bc.z, bc.w};
            const float b_s[4] = {bs.x, bs.y, bs.z, bs.w};
            #pragma unroll
            for (int i = 0; i < 4; i++)
                #pragma unroll
                for (int j = 0; j < 4; j++)
                    acc[i][j] += a_r[i]*b_c[j] + a_i[i]*b_s[j];
        }
        __syncthreads();
    }

    // Epilogue: apply window, fused overlap-add via atomics.
    #pragma unroll
    for (int i = 0; i < 4; i++) {
        const int m = m0 + ty*4 + i;
        const int b = m / TFRAMES;
        const int t = m - b * TFRAMES;
        const size_t obase = (size_t)b * OUT_LEN + (size_t)t * STEP;
        #pragma unroll
        for (int j = 0; j < 4; j++) {
            const int n = n0 + tx*4 + j;
            atomicAdd(&out[obase + n], acc[i][j] * window[n]);
        }
    }
}

extern "C" void kernel_launch(void* const* d_in, const int* in_sizes, int n_in,
                              void* d_out, int out_size, void* d_ws, size_t ws_size,
                              hipStream_t stream) {
    const float* sre    = (const float*)d_in[0];
    const float* sim    = (const float*)d_in[1];
    const float* dcos   = (const float*)d_in[2];
    const float* dsin   = (const float*)d_in[3];
    const float* window = (const float*)d_in[4];
    float* out = (float*)d_out;

    // Output is poisoned with 0xAA before every launch; OLA accumulates -> zero it.
    hipMemsetAsync(out, 0, (size_t)out_size * sizeof(float), stream);

    const int grid = (M_TOTAL / MT) * (NFFT / NT);   // 500 * 16 = 8000 blocks
    istft_gemm_ola<<<grid, 256, 0, stream>>>(sre, sim, dcos, dsin, window, out);
}

// Round 2
// 317.329 us; speedup vs baseline: 7.9275x; 7.9275x over previous
//
#include <hip/hip_runtime.h>

#define BATCH 16
#define TFRAMES 2000
#define BINS 513
#define NFFT 1024
#define STEP 256
#define OUT_LEN 512768            // (TFRAMES-1)*STEP + NFFT
#define M_TOTAL (BATCH*TFRAMES)   // 32000
#define KP 1056                   // 2*513 = 1026 padded to 33*32
#define KPAIRS 528                // KP/2

typedef _Float16 f16x8 __attribute__((ext_vector_type(8)));
typedef float    f32x4 __attribute__((ext_vector_type(4)));

// ---------------- pack kernels ----------------
// A[m][2k] = w_k*re[m][k], A[m][2k+1] = -w_k*im[m][k]; zeros for k>=513.
__global__ __launch_bounds__(256) void pack_A(const float* __restrict__ sre,
                                              const float* __restrict__ sim,
                                              unsigned* __restrict__ Au)
{
    int idx = blockIdx.x * 256 + threadIdx.x;        // m*KPAIRS + p, exact grid
    int m = idx / KPAIRS;
    int k = idx - m * KPAIRS;                        // pair index == bin index
    float a0 = 0.f, a1 = 0.f;
    if (k < BINS) {
        const float w = (k == 0 || k == 512) ? (1.0f/1024.0f) : (2.0f/1024.0f);
        const size_t base = (size_t)m * BINS + k;
        a0 =  w * sre[base];
        a1 = -w * sim[base];
    }
    union { _Float16 h[2]; unsigned u; } pk;
    pk.h[0] = (_Float16)a0;
    pk.h[1] = (_Float16)a1;
    Au[idx] = pk.u;
}

// B[n][2k] = cos[n][k], B[n][2k+1] = sin[n][k]; zeros for k>=513.
__global__ __launch_bounds__(256) void pack_B(const float* __restrict__ dcos,
                                              const float* __restrict__ dsin,
                                              unsigned* __restrict__ Bu)
{
    int idx = blockIdx.x * 256 + threadIdx.x;        // n*KPAIRS + p, exact grid
    int n = idx / KPAIRS;
    int k = idx - n * KPAIRS;
    float b0 = 0.f, b1 = 0.f;
    if (k < BINS) {
        const size_t base = (size_t)n * NFFT + k;
        b0 = dcos[base];
        b1 = dsin[base];
    }
    union { _Float16 h[2]; unsigned u; } pk;
    pk.h[0] = (_Float16)b0;
    pk.h[1] = (_Float16)b1;
    Bu[idx] = pk.u;
}

// ---------------- MFMA GEMM ----------------
#define BM 128
#define BN 128
#define BK 32

__device__ __forceinline__ void async_copy16(const void* g, void* l) {
    __builtin_amdgcn_global_load_lds(
        (const __attribute__((address_space(1))) unsigned*)g,
        (__attribute__((address_space(3))) unsigned*)l, 16, 0, 0);
}

// frames[m][n] = windowed IDFT frame (f32) -- or atomic-OLA directly to out.
template<bool USE_FRAMES>
__global__ __launch_bounds__(256) void gemm_f16(const _Float16* __restrict__ A,
                                                const _Float16* __restrict__ B,
                                                const float* __restrict__ window,
                                                float* __restrict__ frames,
                                                float* __restrict__ out)
{
    __shared__ _Float16 As[BM * BK];   // row-major [128][32], rows = 64B
    __shared__ _Float16 Bs[BN * BK];

    const int bid = blockIdx.x;
    const int nt = bid & 7;            // 8 n-tiles fastest -> A slab L2 reuse
    const int mt = bid >> 3;           // 250 m-tiles
    const int m0 = mt * BM;
    const int n0 = nt * BN;

    const int tid  = threadIdx.x;
    const int w    = tid >> 6;         // wave 0..3
    const int lane = tid & 63;
    const int wm   = w & 1;            // wave's 64x64 quadrant
    const int wn   = w >> 1;
    const int row16 = lane & 15;
    const int quad  = lane >> 4;

    // staging: wave w loads rows [w*32, w*32+32) of both tiles, 2 instrs each
    const _Float16* gA0 = A + (size_t)(m0 + w*32 + (lane >> 2)) * KP + (lane & 3) * 8;
    const _Float16* gB0 = B + (size_t)(n0 + w*32 + (lane >> 2)) * KP + (lane & 3) * 8;
    _Float16* lA0 = As + w * 1024;     // 32 rows * 32 halves
    _Float16* lA1 = lA0 + 512;
    _Float16* lB0 = Bs + w * 1024;
    _Float16* lB1 = lB0 + 512;

    f32x4 acc[4][4] = {};

    for (int k0 = 0; k0 < KP; k0 += BK) {
        async_copy16(gA0 + k0,           lA0);
        async_copy16(gA0 + 16*KP + k0,   lA1);
        async_copy16(gB0 + k0,           lB0);
        async_copy16(gB0 + 16*KP + k0,   lB1);
        __syncthreads();               // drain staging

        f16x8 af[4], bf[4];
        #pragma unroll
        for (int i = 0; i < 4; i++)
            af[i] = *(const f16x8*)&As[(wm*64 + i*16 + row16) * BK + quad*8];
        #pragma unroll
        for (int j = 0; j < 4; j++)
            bf[j] = *(const f16x8*)&Bs[(wn*64 + j*16 + row16) * BK + quad*8];

        #pragma unroll
        for (int i = 0; i < 4; i++)
            #pragma unroll
            for (int j = 0; j < 4; j++)
                acc[i][j] = __builtin_amdgcn_mfma_f32_16x16x32_f16(af[i], bf[j], acc[i][j], 0, 0, 0);

        __syncthreads();               // all waves done reading before overwrite
    }

    // Epilogue. C/D layout: col = lane&15, row = quad*4 + reg.
    #pragma unroll
    for (int j = 0; j < 4; j++) {
        const int n = n0 + wn*64 + j*16 + row16;
        const float win = window[n];
        #pragma unroll
        for (int i = 0; i < 4; i++) {
            const int mrow = m0 + wm*64 + i*16 + quad*4;
            const f32x4 c = acc[i][j];
            if (USE_FRAMES) {
                #pragma unroll
                for (int r = 0; r < 4; r++)
                    frames[(size_t)(mrow + r) * NFFT + n] = c[r] * win;
            } else {
                #pragma unroll
                for (int r = 0; r < 4; r++) {
                    const int m = mrow + r;
                    const int b = m / TFRAMES;
                    const int t = m - b * TFRAMES;
                    atomicAdd(&out[(size_t)b * OUT_LEN + (size_t)t * STEP + n], c[r] * win);
                }
            }
        }
    }
}

// ---------------- deterministic overlap-add gather ----------------
__global__ __launch_bounds__(256) void ola_gather(const float* __restrict__ frames,
                                                  float* __restrict__ out)
{
    const int idx = blockIdx.x * 256 + threadIdx.x;   // exact: BATCH*OUT_LEN % 256 == 0
    const int b = idx / OUT_LEN;
    const int s = idx - b * OUT_LEN;
    int tlo = (s - 768) >> 8;  if (tlo < 0) tlo = 0;          // ceil((s-1023)/256)
    int thi = s >> 8;          if (thi > TFRAMES-1) thi = TFRAMES-1;
    float sum = 0.f;
    for (int t = tlo; t <= thi; ++t)
        sum += frames[((size_t)b * TFRAMES + t) * NFFT + (s - (t << 8))];
    out[idx] = sum;
}

// ---------------- round-1 fp32 fallback (known-correct) ----------------
#define MT 64
#define NT 64
#define KT 16
#define PAD 4
__global__ __launch_bounds__(256) void istft_gemm_ola_f32(
    const float* __restrict__ sre, const float* __restrict__ sim,
    const float* __restrict__ dcos, const float* __restrict__ dsin,
    const float* __restrict__ window, float* __restrict__ out)
{
    __shared__ float As_re[KT][MT + PAD];
    __shared__ float As_im[KT][MT + PAD];
    __shared__ float Bs_c[KT][NT + PAD];
    __shared__ float Bs_s[KT][NT + PAD];
    const int ntile = blockIdx.x & 15;
    const int mtile = blockIdx.x >> 4;
    const int m0 = mtile * MT, n0 = ntile * NT;
    const int tid = threadIdx.x;
    const int tx = tid & 15, ty = tid >> 4;
    const int lcol = tid & 15, lrow = tid >> 4;
    float acc[4][4] = {};
    for (int k0 = 0; k0 < BINS; k0 += KT) {
        const int k = k0 + lcol;
        const bool kvalid = (k < BINS);
        const float w = kvalid ? ((k == 0 || k == 512) ? (1.0f/1024.0f) : (2.0f/1024.0f)) : 0.0f;
        #pragma unroll
        for (int i = 0; i < 4; i++) {
            const int m = m0 + lrow + i*16;
            const size_t base = (size_t)m * BINS + k;
            As_re[lcol][lrow + i*16] = kvalid ?  w * sre[base] : 0.0f;
            As_im[lcol][lrow + i*16] = kvalid ? -w * sim[base] : 0.0f;
        }
        #pragma unroll
        for (int i = 0; i < 4; i++) {
            const int n = n0 + lrow + i*16;
            const size_t base = (size_t)n * NFFT + k;
            Bs_c[lcol][lrow + i*16] = kvalid ? dcos[base] : 0.0f;
            Bs_s[lcol][lrow + i*16] = kvalid ? dsin[base] : 0.0f;
        }
        __syncthreads();
        #pragma unroll
        for (int kk = 0; kk < KT; kk++) {
            const float4 ar = *(const float4*)&As_re[kk][ty*4];
            const float4 ai = *(const float4*)&As_im[kk][ty*4];
            const float4 bc = *(const float4*)&Bs_c[kk][tx*4];
            const float4 bs = *(const float4*)&Bs_s[kk][tx*4];
            const float a_r[4] = {ar.x, ar.y, ar.z, ar.w};
            const float a_i[4] = {ai.x, ai.y, ai.z, ai.w};
            const float b_c[4] = {bc.x, bc.y, bc.z, bc.w};
            const float b_s[4] = {bs.x, bs.y, bs.z, bs.w};
            #pragma unroll
            for (int i = 0; i < 4; i++)
                #pragma unroll
                for (int j = 0; j < 4; j++)
                    acc[i][j] += a_r[i]*b_c[j] + a_i[i]*b_s[j];
        }
        __syncthreads();
    }
    #pragma unroll
    for (int i = 0; i < 4; i++) {
        const int m = m0 + ty*4 + i;
        const int b = m / TFRAMES;
        const int t = m - b * TFRAMES;
        const size_t obase = (size_t)b * OUT_LEN + (size_t)t * STEP;
        #pragma unroll
        for (int j = 0; j < 4; j++) {
            const int n = n0 + tx*4 + j;
            atomicAdd(&out[obase + n], acc[i][j] * window[n]);
        }
    }
}

// ---------------- launch ----------------
extern "C" void kernel_launch(void* const* d_in, const int* in_sizes, int n_in,
                              void* d_out, int out_size, void* d_ws, size_t ws_size,
                              hipStream_t stream) {
    const float* sre    = (const float*)d_in[0];
    const float* sim    = (const float*)d_in[1];
    const float* dcos   = (const float*)d_in[2];
    const float* dsin   = (const float*)d_in[3];
    const float* window = (const float*)d_in[4];
    float* out = (float*)d_out;

    const size_t WS_A      = (size_t)M_TOTAL * KP * sizeof(_Float16);  //  67,584,000
    const size_t WS_B      = (size_t)NFFT    * KP * sizeof(_Float16);  //   2,162,688
    const size_t WS_FRAMES = (size_t)M_TOTAL * NFFT * sizeof(float);   // 131,072,000

    if (ws_size >= WS_A + WS_B) {
        _Float16* Apk    = (_Float16*)d_ws;
        _Float16* Bpk    = (_Float16*)((char*)d_ws + WS_A);
        float*    frames = (float*)   ((char*)d_ws + WS_A + WS_B);
        const bool have_frames = (ws_size >= WS_A + WS_B + WS_FRAMES);

        pack_A<<<(M_TOTAL * KPAIRS) / 256, 256, 0, stream>>>(sre, sim, (unsigned*)Apk);
        pack_B<<<(NFFT   * KPAIRS) / 256, 256, 0, stream>>>(dcos, dsin, (unsigned*)Bpk);

        const int grid = (M_TOTAL / BM) * (NFFT / BN);   // 250 * 8 = 2000
        if (have_frames) {
            gemm_f16<true><<<grid, 256, 0, stream>>>(Apk, Bpk, window, frames, out);
            ola_gather<<<(BATCH * OUT_LEN) / 256, 256, 0, stream>>>(frames, out);
        } else {
            hipMemsetAsync(out, 0, (size_t)out_size * sizeof(float), stream);
            gemm_f16<false><<<grid, 256, 0, stream>>>(Apk, Bpk, window, nullptr, out);
        }
    } else {
        hipMemsetAsync(out, 0, (size_t)out_size * sizeof(float), stream);
        const int grid = (M_TOTAL / MT) * (NFFT / NT);
        istft_gemm_ola_f32<<<grid, 256, 0, stream>>>(sre, sim, dcos, dsin, window, out);
    }
}

// Round 3
// 267.443 us; speedup vs baseline: 9.4062x; 1.1865x over previous
//
#include <hip/hip_runtime.h>

#define BATCH 16
#define TFRAMES 2000
#define BINS 513
#define NFFT 1024
#define STEP 256
#define OUT_LEN 512768            // (TFRAMES-1)*STEP + NFFT
#define M_TOTAL (BATCH*TFRAMES)   // 32000
#define KP 1088                   // 2*513 = 1026 padded to 17*64
#define KPAIRS 544                // KP/2

typedef _Float16 f16x8 __attribute__((ext_vector_type(8)));
typedef float    f32x4 __attribute__((ext_vector_type(4)));

// ---------------- pack kernels ----------------
// A[m][2k] = w_k*re[m][k], A[m][2k+1] = -w_k*im[m][k]; zeros for k>=513.
__global__ __launch_bounds__(256) void pack_A(const float* __restrict__ sre,
                                              const float* __restrict__ sim,
                                              unsigned* __restrict__ Au)
{
    int idx = blockIdx.x * 256 + threadIdx.x;        // m*KPAIRS + p, exact grid
    int m = idx / KPAIRS;
    int k = idx - m * KPAIRS;                        // pair index == bin index
    float a0 = 0.f, a1 = 0.f;
    if (k < BINS) {
        const float w = (k == 0 || k == 512) ? (1.0f/1024.0f) : (2.0f/1024.0f);
        const size_t base = (size_t)m * BINS + k;
        a0 =  w * sre[base];
        a1 = -w * sim[base];
    }
    union { _Float16 h[2]; unsigned u; } pk;
    pk.h[0] = (_Float16)a0;
    pk.h[1] = (_Float16)a1;
    Au[idx] = pk.u;
}

// B[n][2k] = cos[n][k], B[n][2k+1] = sin[n][k]; zeros for k>=513.
__global__ __launch_bounds__(256) void pack_B(const float* __restrict__ dcos,
                                              const float* __restrict__ dsin,
                                              unsigned* __restrict__ Bu)
{
    int idx = blockIdx.x * 256 + threadIdx.x;        // n*KPAIRS + p, exact grid
    int n = idx / KPAIRS;
    int k = idx - n * KPAIRS;
    float b0 = 0.f, b1 = 0.f;
    if (k < BINS) {
        const size_t base = (size_t)n * NFFT + k;
        b0 = dcos[base];
        b1 = dsin[base];
    }
    union { _Float16 h[2]; unsigned u; } pk;
    pk.h[0] = (_Float16)b0;
    pk.h[1] = (_Float16)b1;
    Bu[idx] = pk.u;
}

// ---------------- MFMA GEMM ----------------
#define BM 128
#define BN 128
#define BK 64    // halves per k-iter (2 MFMA k-chunks); 17 iters over KP=1088

__device__ __forceinline__ void async_copy16(const void* g, void* l) {
    __builtin_amdgcn_global_load_lds(
        (const __attribute__((address_space(1))) unsigned*)g,
        (__attribute__((address_space(3))) unsigned*)l, 16, 0, 0);
}

// LDS layout: tile[128 rows][8 chunks of 16B], chunk stored at slot (chunk ^ (row&7)).
// Staging (lane-contiguous LDS, swizzle applied to the GLOBAL address):
//   lane L, instr t of wave w covers row = w*32 + t*8 + (L>>3), stored slot = L&7,
//   i.e. global chunk = (L&7) ^ ((L>>3)&7)  -- t,w drop out mod 8.
// Fragment reads hit chunk (c*4+quad) ^ (row16&7): per 16-lane phase each 4-bank
// group is touched exactly twice -> 2-way = free (m136).
template<bool USE_FRAMES>
__global__ __launch_bounds__(256, 3) void gemm_f16(const _Float16* __restrict__ A,
                                                   const _Float16* __restrict__ B,
                                                   const float* __restrict__ window,
                                                   _Float16* __restrict__ frames,
                                                   float* __restrict__ out)
{
    __shared__ _Float16 As[BM * BK];   // 16 KB
    __shared__ _Float16 Bs[BN * BK];   // 16 KB

    // XCD-grouping swizzle: keep the 8 n-tiles of one m-slab on one XCD.
    const int raw = blockIdx.x;                    // 0..1999
    const int idx = (raw & 7) * 250 + (raw >> 3);  // bijection
    const int mt = idx >> 3;                       // 0..249
    const int nt = idx & 7;                        // 0..7
    const int m0 = mt * BM;
    const int n0 = nt * BN;

    const int tid  = threadIdx.x;
    const int w    = tid >> 6;         // wave 0..3
    const int lane = tid & 63;
    const int wm   = w & 1;            // wave's 64x64 quadrant
    const int wn   = w >> 1;
    const int row16 = lane & 15;
    const int quad  = lane >> 4;

    // staging addresses
    const int srow   = lane >> 3;                    // 0..7
    const int schunk = (lane & 7) ^ srow;            // swizzled chunk for this lane
    const _Float16* gA = A + (size_t)(m0 + w*32 + srow) * KP + schunk * 8;
    const _Float16* gB = B + (size_t)(n0 + w*32 + srow) * KP + schunk * 8;

    f32x4 acc[4][4] = {};

    for (int k0 = 0; k0 < KP; k0 += BK) {
        #pragma unroll
        for (int t = 0; t < 4; t++) {
            async_copy16(gA + (size_t)t*8*KP + k0, As + (w*4 + t) * 512);
            async_copy16(gB + (size_t)t*8*KP + k0, Bs + (w*4 + t) * 512);
        }
        __syncthreads();               // drain staging

        #pragma unroll
        for (int c = 0; c < 2; c++) {
            f16x8 af[4], bf[4];
            #pragma unroll
            for (int i = 0; i < 4; i++) {
                const int rowA = wm*64 + i*16 + row16;
                const int chA  = (c*4 + quad) ^ (row16 & 7);
                af[i] = *(const f16x8*)&As[rowA * BK + chA * 8];
            }
            #pragma unroll
            for (int j = 0; j < 4; j++) {
                const int rowB = wn*64 + j*16 + row16;
                const int chB  = (c*4 + quad) ^ (row16 & 7);
                bf[j] = *(const f16x8*)&Bs[rowB * BK + chB * 8];
            }
            #pragma unroll
            for (int i = 0; i < 4; i++)
                #pragma unroll
                for (int j = 0; j < 4; j++)
                    acc[i][j] = __builtin_amdgcn_mfma_f32_16x16x32_f16(af[i], bf[j], acc[i][j], 0, 0, 0);
        }

        __syncthreads();               // all waves done reading before overwrite
    }

    // Epilogue. C/D layout: col = lane&15, row = quad*4 + reg.
    #pragma unroll
    for (int j = 0; j < 4; j++) {
        const int n = n0 + wn*64 + j*16 + row16;
        const float win = window[n];
        #pragma unroll
        for (int i = 0; i < 4; i++) {
            const int mrow = m0 + wm*64 + i*16 + quad*4;
            const f32x4 c = acc[i][j];
            if (USE_FRAMES) {
                #pragma unroll
                for (int r = 0; r < 4; r++)
                    frames[(size_t)(mrow + r) * NFFT + n] = (_Float16)(c[r] * win);
            } else {
                #pragma unroll
                for (int r = 0; r < 4; r++) {
                    const int m = mrow + r;
                    const int b = m / TFRAMES;
                    const int t = m - b * TFRAMES;
                    atomicAdd(&out[(size_t)b * OUT_LEN + (size_t)t * STEP + n], c[r] * win);
                }
            }
        }
    }
}

// ---------------- deterministic overlap-add gather ----------------
__global__ __launch_bounds__(256) void ola_gather(const _Float16* __restrict__ frames,
                                                  float* __restrict__ out)
{
    const int idx = blockIdx.x * 256 + threadIdx.x;   // exact: BATCH*OUT_LEN % 256 == 0
    const int b = idx / OUT_LEN;
    const int s = idx - b * OUT_LEN;
    int tlo = (s - 768) >> 8;  if (tlo < 0) tlo = 0;          // ceil((s-1023)/256)
    int thi = s >> 8;          if (thi > TFRAMES-1) thi = TFRAMES-1;
    float sum = 0.f;
    for (int t = tlo; t <= thi; ++t)
        sum += (float)frames[((size_t)b * TFRAMES + t) * NFFT + (s - (t << 8))];
    out[idx] = sum;
}

// ---------------- round-1 fp32 fallback (known-correct) ----------------
#define MT 64
#define NT 64
#define KT 16
#define PAD 4
__global__ __launch_bounds__(256) void istft_gemm_ola_f32(
    const float* __restrict__ sre, const float* __restrict__ sim,
    const float* __restrict__ dcos, const float* __restrict__ dsin,
    const float* __restrict__ window, float* __restrict__ out)
{
    __shared__ float As_re[KT][MT + PAD];
    __shared__ float As_im[KT][MT + PAD];
    __shared__ float Bs_c[KT][NT + PAD];
    __shared__ float Bs_s[KT][NT + PAD];
    const int ntile = blockIdx.x & 15;
    const int mtile = blockIdx.x >> 4;
    const int m0 = mtile * MT, n0 = ntile * NT;
    const int tid = threadIdx.x;
    const int tx = tid & 15, ty = tid >> 4;
    const int lcol = tid & 15, lrow = tid >> 4;
    float acc[4][4] = {};
    for (int k0 = 0; k0 < BINS; k0 += KT) {
        const int k = k0 + lcol;
        const bool kvalid = (k < BINS);
        const float w = kvalid ? ((k == 0 || k == 512) ? (1.0f/1024.0f) : (2.0f/1024.0f)) : 0.0f;
        #pragma unroll
        for (int i = 0; i < 4; i++) {
            const int m = m0 + lrow + i*16;
            const size_t base = (size_t)m * BINS + k;
            As_re[lcol][lrow + i*16] = kvalid ?  w * sre[base] : 0.0f;
            As_im[lcol][lrow + i*16] = kvalid ? -w * sim[base] : 0.0f;
        }
        #pragma unroll
        for (int i = 0; i < 4; i++) {
            const int n = n0 + lrow + i*16;
            const size_t base = (size_t)n * NFFT + k;
            Bs_c[lcol][lrow + i*16] = kvalid ? dcos[base] : 0.0f;
            Bs_s[lcol][lrow + i*16] = kvalid ? dsin[base] : 0.0f;
        }
        __syncthreads();
        #pragma unroll
        for (int kk = 0; kk < KT; kk++) {
            const float4 ar = *(const float4*)&As_re[kk][ty*4];
            const float4 ai = *(const float4*)&As_im[kk][ty*4];
            const float4 bc = *(const float4*)&Bs_c[kk][tx*4];
            const float4 bs = *(const float4*)&Bs_s[kk][tx*4];
            const float a_r[4] = {ar.x, ar.y, ar.z, ar.w};
            const float a_i[4] = {ai.x, ai.y, ai.z, ai.w};
            const float b_c[4] = {bc.x, bc.y, bc.z, bc.w};
            const float b_s[4] = {bs.x, bs.y, bs.z, bs.w};
            #pragma unroll
            for (int i = 0; i < 4; i++)
                #pragma unroll
                for (int j = 0; j < 4; j++)
                    acc[i][j] += a_r[i]*b_c[j] + a_i[i]*b_s[j];
        }
        __syncthreads();
    }
    #pragma unroll
    for (int i = 0; i < 4; i++) {
        const int m = m0 + ty*4 + i;
        const int b = m / TFRAMES;
        const int t = m - b * TFRAMES;
        const size_t obase = (size_t)b * OUT_LEN + (size_t)t * STEP;
        #pragma unroll
        for (int j = 0; j < 4; j++) {
            const int n = n0 + tx*4 + j;
            atomicAdd(&out[obase + n], acc[i][j] * window[n]);
        }
    }
}

// ---------------- launch ----------------
extern "C" void kernel_launch(void* const* d_in, const int* in_sizes, int n_in,
                              void* d_out, int out_size, void* d_ws, size_t ws_size,
                              hipStream_t stream) {
    const float* sre    = (const float*)d_in[0];
    const float* sim    = (const float*)d_in[1];
    const float* dcos   = (const float*)d_in[2];
    const float* dsin   = (const float*)d_in[3];
    const float* window = (const float*)d_in[4];
    float* out = (float*)d_out;

    const size_t WS_A      = (size_t)M_TOTAL * KP * sizeof(_Float16);    // 69,632,000
    const size_t WS_B      = (size_t)NFFT    * KP * sizeof(_Float16);    //  2,228,224
    const size_t WS_FRAMES = (size_t)M_TOTAL * NFFT * sizeof(_Float16);  // 65,536,000

    if (ws_size >= WS_A + WS_B) {
        _Float16* Apk    = (_Float16*)d_ws;
        _Float16* Bpk    = (_Float16*)((char*)d_ws + WS_A);
        _Float16* frames = (_Float16*)((char*)d_ws + WS_A + WS_B);
        const bool have_frames = (ws_size >= WS_A + WS_B + WS_FRAMES);

        pack_A<<<(M_TOTAL * KPAIRS) / 256, 256, 0, stream>>>(sre, sim, (unsigned*)Apk);
        pack_B<<<(NFFT   * KPAIRS) / 256, 256, 0, stream>>>(dcos, dsin, (unsigned*)Bpk);

        const int grid = (M_TOTAL / BM) * (NFFT / BN);   // 250 * 8 = 2000
        if (have_frames) {
            gemm_f16<true><<<grid, 256, 0, stream>>>(Apk, Bpk, window, frames, out);
            ola_gather<<<(BATCH * OUT_LEN) / 256, 256, 0, stream>>>(frames, out);
        } else {
            hipMemsetAsync(out, 0, (size_t)out_size * sizeof(float), stream);
            gemm_f16<false><<<grid, 256, 0, stream>>>(Apk, Bpk, window, nullptr, out);
        }
    } else {
        hipMemsetAsync(out, 0, (size_t)out_size * sizeof(float), stream);
        const int grid = (M_TOTAL / MT) * (NFFT / NT);
        istft_gemm_ola_f32<<<grid, 256, 0, stream>>>(sre, sim, dcos, dsin, window, out);
    }
}